// Round 25
// baseline (281.718 us; speedup 1.0000x reference)
//
#include <hip/hip_runtime.h>
#include <hip/hip_bf16.h>
#include <cstdint>

typedef __attribute__((ext_vector_type(4))) float f32x4;
typedef __attribute__((ext_vector_type(16))) float f32x16;
typedef _Float16 f16x8 __attribute__((ext_vector_type(8)));
typedef _Float16 f16x4 __attribute__((ext_vector_type(4)));

#define BN_EPS 1e-5f

// ---------------- fp32 -> fp16 cast (only W, 4 MB) ----------------
__global__ __launch_bounds__(256)
void cast_f32_f16(const float* __restrict__ src, _Float16* __restrict__ dst, int n8) {
    int i = blockIdx.x * blockDim.x + threadIdx.x;
    if (i >= n8) return;
    const float4* s4 = (const float4*)src;
    float4 a = s4[2 * (size_t)i];
    float4 b = s4[2 * (size_t)i + 1];
    f16x8 h;
    h[0] = (_Float16)a.x; h[1] = (_Float16)a.y; h[2] = (_Float16)a.z; h[3] = (_Float16)a.w;
    h[4] = (_Float16)b.x; h[5] = (_Float16)b.y; h[6] = (_Float16)b.z; h[7] = (_Float16)b.w;
    *(f16x8*)(dst + 8 * (size_t)i) = h;
}

// async global->LDS, 16B per lane, wave-uniform LDS base (B path)
__device__ __forceinline__ void async16(const char* g, char* l) {
    __builtin_amdgcn_global_load_lds(
        (const __attribute__((address_space(1))) unsigned int*)(uintptr_t)g,
        (__attribute__((address_space(3))) unsigned int*)(uintptr_t)l,
        16, 0, 0);
}

// ====== r24 structure (measured best 272us) with 32x32x16 MFMA ======
// Swap basis: 32x32 pipe efficiency 2382 vs 2075 TF (m119/m06) + half the MFMA instr count.
// Conflict analysis (this layout, enumerated): fragment b128 at row base+cl, phys slot
// (2j+hl)^((cl>>1)&3): 8 lanes per 4-bank slot group = exact 8-cyc minimum, conflict-free.
// mf*2048 / nf*2048 / wr*128 / wc*64 bases don't perturb the XOR (16 == 0 mod 4).
// C/D layout (m74/m101 verified, field-tested r5): col=cl, row=(j&3)+8*(j>>2)+4*hl.
// Everything else byte-identical to r24: order (c)(a)(b)(d,e)(f,g); FIFO ledger
// {A=8 reg loads, B=4 asyncs}, vmcnt(8) steady, tails vmcnt(0)/compute-only;
// A-write->ABUF((kt+1)&1) WAR-safe; no setprio (r21); BK=64 (r20); lgkm rule (r23).

#define ABUF(t) (lds + ((t) & 1) * 32768)
#define BBUF(t) (lds + 65536 + ((t) & 1) * 32768)

__device__ __forceinline__ void cvtWrite(char* addr, const f32x4& v) {
    f16x4 h;
    h[0] = (_Float16)v[0]; h[1] = (_Float16)v[1];
    h[2] = (_Float16)v[2]; h[3] = (_Float16)v[3];
    *(f16x4*)addr = h;
}

template<int WAITN, bool STAGEA, bool STAGEB, bool WRITEA, bool BAR>
__device__ __forceinline__ void ktile(
    int kt, char* lds, const float* aBase, size_t aRowStep,
    const char* b0, const char* b1, int widB,
    int aoffs, int boffs, const int (&wA)[4], f32x4 (&rA)[8],
    f32x16 (&acc)[4][2])
{
    // (c) B(kt+1): 4 asyncs (two k-halves x two row-chunks)
    if (STAGEB) {
        const size_t cb = (size_t)(kt + 1) * 128;
        char* d = BBUF(kt + 1);
        async16(b0 + cb,      d + widB);
        async16(b1 + cb,      d + 8192 + widB);
        async16(b0 + cb + 64, d + 16384 + widB);
        async16(b1 + cb + 64, d + 24576 + widB);
    }
    // (a) cvt + ds_write A(kt+1) (both halves)
    if (WRITEA) {
        char* ad = ABUF(kt + 1);
        #pragma unroll
        for (int h = 0; h < 2; ++h)
            #pragma unroll
            for (int j = 0; j < 4; ++j)
                cvtWrite(ad + h * 16384 + wA[j], rA[h * 4 + j]);
    }
    // (b) A(kt+2) -> rA
    if (STAGEA) {
        #pragma unroll
        for (int h = 0; h < 2; ++h)
            #pragma unroll
            for (int j = 0; j < 4; ++j)
                rA[h * 4 + j] = *(const f32x4*)(aBase + j * aRowStep + (size_t)(kt + 2) * 64 + h * 32);
    }
    // (d,e) two k-halves: 12 ds_read + 16 MFMA(32x32x16) each
    #pragma unroll
    for (int h = 0; h < 2; ++h) {
        f16x8 aj0[4], aj1[4], bj0[2], bj1[2];
        const char* ab = ABUF(kt) + h * 16384;
        const char* bb = BBUF(kt) + h * 16384;
        #pragma unroll
        for (int nf = 0; nf < 2; ++nf) bj0[nf] = *(const f16x8*)(bb + boffs + nf * 2048);
        #pragma unroll
        for (int mf = 0; mf < 4; ++mf) aj0[mf] = *(const f16x8*)(ab + aoffs + mf * 2048);
        #pragma unroll
        for (int nf = 0; nf < 2; ++nf) bj1[nf] = *(const f16x8*)(bb + (boffs ^ 32) + nf * 2048);
        #pragma unroll
        for (int mf = 0; mf < 4; ++mf) aj1[mf] = *(const f16x8*)(ab + (aoffs ^ 32) + mf * 2048);
        #pragma unroll
        for (int mf = 0; mf < 4; ++mf)
            #pragma unroll
            for (int nf = 0; nf < 2; ++nf)
                acc[mf][nf] = __builtin_amdgcn_mfma_f32_32x32x16_f16(aj0[mf], bj0[nf], acc[mf][nf], 0, 0, 0);
        #pragma unroll
        for (int mf = 0; mf < 4; ++mf)
            #pragma unroll
            for (int nf = 0; nf < 2; ++nf)
                acc[mf][nf] = __builtin_amdgcn_mfma_f32_32x32x16_f16(aj1[mf], bj1[nf], acc[mf][nf], 0, 0, 0);
    }
    // (f,g)
    if (WAITN == 8)      { asm volatile("s_waitcnt vmcnt(8)" ::: "memory"); }
    else if (WAITN == 0) { asm volatile("s_waitcnt vmcnt(0)" ::: "memory"); }
    if (BAR) {
        asm volatile("s_waitcnt lgkmcnt(0)" ::: "memory");
        __builtin_amdgcn_s_barrier();
    }
}

__global__ __launch_bounds__(512, 2)
void gemm_gbn_kernel(const float* __restrict__ Af,
                     const _Float16* __restrict__ Bw,
                     const float* __restrict__ priors,
                     const float* __restrict__ gamma,
                     const float* __restrict__ beta,
                     _Float16* __restrict__ Zh,
                     int M, int N, int K)
{
    __shared__ __align__(16) char lds[131072];   // A 2x32KB + B 2x32KB

    const int tid  = threadIdx.x;
    const int lane = tid & 63;
    const int wid  = tid >> 6;     // 0..7
    const int wr   = wid >> 2;     // 0..1  (128-row half == one virtual batch)
    const int wc   = wid & 3;      // 0..3  (64-col slice)
    const int cl   = lane & 31;    // 32x32 fragment row/col
    const int hl   = lane >> 5;    // k-sub-half within 16-k slice

    // XCD-aware bijective swizzle (512 blocks, %8==0)
    const int bid = blockIdx.x;
    const int swz = (bid & 7) * 64 + (bid >> 3);
    const int row0 = (swz >> 2) * 256;
    const int col0 = (swz & 3) * 256;

    // ---- A fused-cast staging (unchanged, proven): row (tid>>3)+j*64, granule tid&7 ----
    const float* aBase = Af + (size_t)(row0 + (tid >> 3)) * (size_t)K + (tid & 7) * 4;
    const size_t aRowStep = (size_t)64 * K;
    int wA[4];
    {
        const int sub = tid & 7;
        #pragma unroll
        for (int j = 0; j < 4; ++j) {
            const int r = (tid >> 3) + j * 64;
            wA[j] = r * 64 + (((sub >> 1) ^ ((r >> 1) & 3)) * 16) + (sub & 1) * 8;
        }
    }

    // ---- B staging (proven gload_lds path) ----
    const int bperm = ((tid & 3) ^ ((tid >> 3) & 3)) * 16;
    const char* b0 = (const char*)Bw + (size_t)(col0 + (tid >> 2)) * (size_t)K * 2 + bperm;
    const char* b1 = b0 + (size_t)128 * K * 2;
    const int widB = wid * 1024;

    // ---- 32x32 fragment read offsets (conflict-free per enumeration above) ----
    // j=0 slice at offs; j=1 slice at offs^32 (slot XOR 2). mf/nf add *2048.
    const int sswz = (hl ^ ((cl >> 1) & 3)) * 16;
    const int aoffs = (wr * 128 + cl) * 64 + sswz;
    const int boffs = (wc * 64 + cl) * 64 + sswz;

    f32x16 acc[4][2];
    #pragma unroll
    for (int mf = 0; mf < 4; ++mf)
        #pragma unroll
        for (int nf = 0; nf < 2; ++nf)
            acc[mf][nf] = (f32x16)0.0f;

    const int nt = K >> 6;   // 32 K-tiles of 64
    f32x4 rA[8];

    // ---- prologue: A(0); B(0); cvt+write A(0) [vmcnt(4)]; A(1); vmcnt(8) [retires B(0)] ----
    #pragma unroll
    for (int h = 0; h < 2; ++h)
        #pragma unroll
        for (int j = 0; j < 4; ++j)
            rA[h * 4 + j] = *(const f32x4*)(aBase + j * aRowStep + h * 32);
    {
        char* d = BBUF(0);
        async16(b0,      d + widB);
        async16(b1,      d + 8192 + widB);
        async16(b0 + 64, d + 16384 + widB);
        async16(b1 + 64, d + 24576 + widB);
    }
    #pragma unroll
    for (int h = 0; h < 2; ++h)
        #pragma unroll
        for (int j = 0; j < 4; ++j)
            cvtWrite(ABUF(0) + h * 16384 + wA[j], rA[h * 4 + j]);   // waits A(0): vmcnt(4)
    #pragma unroll
    for (int h = 0; h < 2; ++h)
        #pragma unroll
        for (int j = 0; j < 4; ++j)
            rA[h * 4 + j] = *(const f32x4*)(aBase + j * aRowStep + 64 + h * 32);
    asm volatile("s_waitcnt vmcnt(8)" ::: "memory");   // retires B(0); A(1) in flight
    asm volatile("s_waitcnt lgkmcnt(0)" ::: "memory");
    __builtin_amdgcn_s_barrier();

    for (int kt = 0; kt < nt - 2; ++kt)
        ktile<8, true,  true,  true,  true >(kt, lds, aBase, aRowStep, b0, b1, widB, aoffs, boffs, wA, rA, acc);
    ktile<0,  false, true,  true,  true >(nt - 2, lds, aBase, aRowStep, b0, b1, widB, aoffs, boffs, wA, rA, acc);
    ktile<-1, false, false, false, false>(nt - 1, lds, aBase, aRowStep, b0, b1, widB, aoffs, boffs, wA, rA, acc);

    // ---- fused Ghost BatchNorm + priors epilogue (wave-local; z written f16) ----
    // C/D map: col = cl, row = mf*32 + (j&3) + 8*(j>>2) + 4*hl  (m74/m101; r5 field-tested)
    #pragma unroll
    for (int nf = 0; nf < 2; ++nf) {
        float s1 = 0.f, s2 = 0.f;
        #pragma unroll
        for (int mf = 0; mf < 4; ++mf)
            #pragma unroll
            for (int j = 0; j < 16; ++j) {
                float v = acc[mf][nf][j];
                s1 += v; s2 += v * v;
            }
        s1 += __shfl_xor(s1, 32); s2 += __shfl_xor(s2, 32);   // combine hl partner (same cl)
        float mean = s1 * (1.f / 128.f);
        float var  = s2 * (1.f / 128.f) - mean * mean;
        float rstd = rsqrtf(var + BN_EPS);
        const int c = col0 + wc * 64 + nf * 32 + cl;
        float g = gamma[c] * rstd;
        float b = beta[c] - mean * g;
        #pragma unroll
        for (int mf = 0; mf < 4; ++mf)
            #pragma unroll
            for (int j = 0; j < 16; ++j) {
                int r = row0 + wr * 128 + mf * 32 + (j & 3) + 8 * (j >> 2) + 4 * hl;
                size_t off = (size_t)r * N + c;
                Zh[off] = (_Float16)((acc[mf][nf][j] * g + b) * priors[off]);
            }
    }
}

// ---------------- sparsemax: one wave per row (1024), f16 input, exact Michelot ----------------
__device__ __forceinline__ float waveSum(float v) {
    #pragma unroll
    for (int off = 32; off > 0; off >>= 1) v += __shfl_xor(v, off);
    return v;
}

__global__ __launch_bounds__(256)
void sparsemax_kernel(const _Float16* __restrict__ Zh, float* __restrict__ Out) {
    const int lane = threadIdx.x & 63;
    const int wid  = threadIdx.x >> 6;
    const size_t row = (size_t)blockIdx.x * 4 + wid;
    const f16x8* zr = (const f16x8*)(Zh + row * 1024);

    float p[16];
    #pragma unroll
    for (int j = 0; j < 2; ++j) {
        f16x8 v = zr[lane * 2 + j];
        #pragma unroll
        for (int e = 0; e < 8; ++e) p[8 * j + e] = (float)v[e];
    }

    float s = 0.f;
    #pragma unroll
    for (int i = 0; i < 16; ++i) s += p[i];
    s = waveSum(s);

    float kc  = 1024.f;
    float tau = (s - 1.f) * (1.f / 1024.f);
    for (int it = 0; it < 64; ++it) {
        float s2 = 0.f, c2 = 0.f;
        #pragma unroll
        for (int i = 0; i < 16; ++i) {
            if (p[i] > tau) { s2 += p[i]; c2 += 1.f; }
        }
        s2 = waveSum(s2); c2 = waveSum(c2);
        if (c2 == kc) break;        // support stable -> tau exact
        kc = c2;
        tau = (s2 - 1.f) / c2;
    }

    float* outr = Out + row * 1024 + lane * 16;
    #pragma unroll
    for (int j = 0; j < 4; ++j) {
        float4 o;
        o.x = fmaxf(p[4 * j + 0] - tau, 0.f);
        o.y = fmaxf(p[4 * j + 1] - tau, 0.f);
        o.z = fmaxf(p[4 * j + 2] - tau, 0.f);
        o.w = fmaxf(p[4 * j + 3] - tau, 0.f);
        *(float4*)(outr + 4 * j) = o;
    }
}

extern "C" void kernel_launch(void* const* d_in, const int* in_sizes, int n_in,
                              void* d_out, int out_size, void* d_ws, size_t ws_size,
                              hipStream_t stream)
{
    const float* priors = (const float*)d_in[0];
    const float* feat   = (const float*)d_in[1];
    const float* W      = (const float*)d_in[2];
    const float* gamma  = (const float*)d_in[3];
    const float* beta   = (const float*)d_in[4];
    float* out = (float*)d_out;

    const int Nf = in_sizes[3];              // 1024
    const int Kf = in_sizes[2] / Nf;         // 2048
    const int Mr = in_sizes[1] / Kf;         // 32768

    _Float16* Wh = (_Float16*)d_ws;                                   // 4 MB
    _Float16* Zh = (_Float16*)((char*)d_ws + (size_t)Nf * Kf * 2);    // 64 MB

    {
        int n8 = Nf * (Kf / 8);
        cast_f32_f16<<<(n8 + 255) / 256, 256, 0, stream>>>(W, Wh, n8);
    }

    int nblk = (Mr / 256) * (Nf / 256);      // 512, divisible by 8
    gemm_gbn_kernel<<<nblk, 512, 0, stream>>>(feat, Wh, priors, gamma, beta, Zh, Mr, Nf, Kf);

    sparsemax_kernel<<<Mr / 4, 256, 0, stream>>>(Zh, out);
}

// Round 26
// 272.110 us; speedup vs baseline: 1.0353x; 1.0353x over previous
//
#include <hip/hip_runtime.h>
#include <hip/hip_bf16.h>
#include <cstdint>

typedef __attribute__((ext_vector_type(4))) float f32x4;
typedef _Float16 f16x8 __attribute__((ext_vector_type(8)));
typedef _Float16 f16x4 __attribute__((ext_vector_type(4)));

#define BN_EPS 1e-5f

// ---------------- fp32 -> fp16 cast (only W, 4 MB) ----------------
__global__ __launch_bounds__(256)
void cast_f32_f16(const float* __restrict__ src, _Float16* __restrict__ dst, int n8) {
    int i = blockIdx.x * blockDim.x + threadIdx.x;
    if (i >= n8) return;
    const float4* s4 = (const float4*)src;
    float4 a = s4[2 * (size_t)i];
    float4 b = s4[2 * (size_t)i + 1];
    f16x8 h;
    h[0] = (_Float16)a.x; h[1] = (_Float16)a.y; h[2] = (_Float16)a.z; h[3] = (_Float16)a.w;
    h[4] = (_Float16)b.x; h[5] = (_Float16)b.y; h[6] = (_Float16)b.z; h[7] = (_Float16)b.w;
    *(f16x8*)(dst + 8 * (size_t)i) = h;
}

// async global->LDS, 16B per lane, wave-uniform LDS base (B path)
__device__ __forceinline__ void async16(const char* g, char* l) {
    __builtin_amdgcn_global_load_lds(
        (const __attribute__((address_space(1))) unsigned int*)(uintptr_t)g,
        (__attribute__((address_space(3))) unsigned int*)(uintptr_t)l,
        16, 0, 0);
}

// ====== FINAL (r21/r24, measured best 271-272us): 256x256, BK=64, fused A-cast ======
// Session conclusions baked in:
//  - 16x16x32 MFMA with this exact read swizzle = the only measured-0-conflict pattern
//    (r25: 32x32 identical perf but 1.26e7 conflicts -> conflicts off critical path).
//  - Order (c)(a)(b)(d,e): ds_writes must precede ds_reads (r23: lgkmcnt is one FIFO;
//    interleaved writes force full drains, +10%).
//  - No setprio (r21: m190-confirmed, lockstep GEMM hurts).
//  - BK=64 > BK=32 (r20, +2%: amortizes per-tile waits/barrier).
//  - min-waves/EU = 2 (r17: acc=128 regs spills catastrophically at 4/EU).
//  - 1 block/CU optimal (r19: 2 blocks/CU = slower; per-wave work halving dominates).
// FIFO ledger per wave/tile {A=8 reg loads, B=4 asyncs}:
//   entering kt: queue [A(kt+1) 8]
//   (c) B(kt+1) 4 asyncs -> BBUF((kt+1)&1)   [queue A8,B4]
//   (a) cvt+write A(kt+1) [compiler vmcnt(4) retires A(kt+1), leaves B(kt+1)]
//   (b) A(kt+2) 8 loads                      [queue B4,A8 = 12]
//   (d) per k-half: 12 ds_read; (e) 32 MFMA  (x2 halves)
//   (f) vmcnt(8) retires B(kt+1)  (g) lgkm0; barrier
// WAR: A-write@kt -> ABUF((kt+1)&1)=ABUF((kt-1)&1), reads drained before barrier@kt-1.
//      B-async@kt -> BBUF((kt+1)&1), reads@kt-1 drained before barrier@kt-1. Safe.
// Tails: kt=nt-2: STAGEA off, vmcnt(0); kt=nt-1: compute only.

#define ABUF(t) (lds + ((t) & 1) * 32768)
#define BBUF(t) (lds + 65536 + ((t) & 1) * 32768)

__device__ __forceinline__ void cvtWrite(char* addr, const f32x4& v) {
    f16x4 h;
    h[0] = (_Float16)v[0]; h[1] = (_Float16)v[1];
    h[2] = (_Float16)v[2]; h[3] = (_Float16)v[3];
    *(f16x4*)addr = h;
}

template<int WAITN, bool STAGEA, bool STAGEB, bool WRITEA, bool BAR>
__device__ __forceinline__ void ktile(
    int kt, char* lds, const float* aBase, size_t aRowStep,
    const char* b0, const char* b1, int widB,
    int aoff, int boff, const int (&wA)[4], f32x4 (&rA)[8],
    f32x4 (&acc)[8][4])
{
    // (c) B(kt+1): 4 asyncs (two k-halves x two row-chunks)
    if (STAGEB) {
        const size_t cb = (size_t)(kt + 1) * 128;
        char* d = BBUF(kt + 1);
        async16(b0 + cb,      d + widB);
        async16(b1 + cb,      d + 8192 + widB);
        async16(b0 + cb + 64, d + 16384 + widB);
        async16(b1 + cb + 64, d + 24576 + widB);
    }
    // (a) cvt + ds_write A(kt+1) (both halves)
    if (WRITEA) {
        char* ad = ABUF(kt + 1);
        #pragma unroll
        for (int h = 0; h < 2; ++h)
            #pragma unroll
            for (int j = 0; j < 4; ++j)
                cvtWrite(ad + h * 16384 + wA[j], rA[h * 4 + j]);
    }
    // (b) A(kt+2) -> rA
    if (STAGEA) {
        #pragma unroll
        for (int h = 0; h < 2; ++h)
            #pragma unroll
            for (int j = 0; j < 4; ++j)
                rA[h * 4 + j] = *(const f32x4*)(aBase + j * aRowStep + (size_t)(kt + 2) * 64 + h * 32);
    }
    // (d,e) two k-halves: 12 ds_read + 32 MFMA each
    #pragma unroll
    for (int h = 0; h < 2; ++h) {
        f16x8 a[8], b[4];
        const char* ab = ABUF(kt) + h * 16384;
        const char* bb = BBUF(kt) + h * 16384;
        #pragma unroll
        for (int n = 0; n < 4; ++n) b[n] = *(const f16x8*)(bb + boff + n * 1024);
        #pragma unroll
        for (int m = 0; m < 8; ++m) a[m] = *(const f16x8*)(ab + aoff + m * 1024);
        #pragma unroll
        for (int m = 0; m < 8; ++m)
            #pragma unroll
            for (int n = 0; n < 4; ++n)
                acc[m][n] = __builtin_amdgcn_mfma_f32_16x16x32_f16(a[m], b[n], acc[m][n], 0, 0, 0);
    }
    // (f,g)
    if (WAITN == 8)      { asm volatile("s_waitcnt vmcnt(8)" ::: "memory"); }
    else if (WAITN == 0) { asm volatile("s_waitcnt vmcnt(0)" ::: "memory"); }
    if (BAR) {
        asm volatile("s_waitcnt lgkmcnt(0)" ::: "memory");
        __builtin_amdgcn_s_barrier();
    }
}

__global__ __launch_bounds__(512, 2)
void gemm_gbn_kernel(const float* __restrict__ Af,
                     const _Float16* __restrict__ Bw,
                     const float* __restrict__ priors,
                     const float* __restrict__ gamma,
                     const float* __restrict__ beta,
                     _Float16* __restrict__ Zh,
                     int M, int N, int K)
{
    __shared__ __align__(16) char lds[131072];   // A 2x32KB + B 2x32KB

    const int tid  = threadIdx.x;
    const int lane = tid & 63;
    const int wid  = tid >> 6;     // 0..7
    const int wr   = wid >> 2;     // 0..1  (128-row half == one virtual batch)
    const int wc   = wid & 3;      // 0..3  (64-col slice)
    const int fr   = lane & 15;
    const int kg   = lane >> 4;

    // XCD-aware bijective swizzle (512 blocks, %8==0)
    const int bid = blockIdx.x;
    const int swz = (bid & 7) * 64 + (bid >> 3);
    const int row0 = (swz >> 2) * 256;
    const int col0 = (swz & 3) * 256;

    // ---- A fused-cast staging: load (h,j) covers row (tid>>3)+j*64, k-half h, granule tid&7 ----
    const float* aBase = Af + (size_t)(row0 + (tid >> 3)) * (size_t)K + (tid & 7) * 4;
    const size_t aRowStep = (size_t)64 * K;
    int wA[4];
    {
        const int sub = tid & 7;
        #pragma unroll
        for (int j = 0; j < 4; ++j) {
            const int r = (tid >> 3) + j * 64;
            wA[j] = r * 64 + (((sub >> 1) ^ ((r >> 1) & 3)) * 16) + (sub & 1) * 8;
        }
    }

    // ---- B staging (proven gload_lds path) ----
    const int bperm = ((tid & 3) ^ ((tid >> 3) & 3)) * 16;
    const char* b0 = (const char*)Bw + (size_t)(col0 + (tid >> 2)) * (size_t)K * 2 + bperm;
    const char* b1 = b0 + (size_t)128 * K * 2;
    const int widB = wid * 1024;

    // ---- fragment read offsets (within 16KB half-buffer; measured-0-conflict swizzle) ----
    int aoff = (wr * 128 + fr) * 64 + kg * 16;
    aoff ^= ((aoff >> 7) & 3) << 4;
    int boff = (wc * 64 + fr) * 64 + kg * 16;
    boff ^= ((boff >> 7) & 3) << 4;

    f32x4 acc[8][4];
    #pragma unroll
    for (int m = 0; m < 8; ++m)
        #pragma unroll
        for (int n = 0; n < 4; ++n)
            acc[m][n] = (f32x4)0.0f;

    const int nt = K >> 6;   // 32 K-tiles of 64
    f32x4 rA[8];

    // ---- prologue: A(0); B(0); cvt+write A(0) [vmcnt(4)]; A(1); vmcnt(8) [retires B(0)] ----
    #pragma unroll
    for (int h = 0; h < 2; ++h)
        #pragma unroll
        for (int j = 0; j < 4; ++j)
            rA[h * 4 + j] = *(const f32x4*)(aBase + j * aRowStep + h * 32);
    {
        char* d = BBUF(0);
        async16(b0,      d + widB);
        async16(b1,      d + 8192 + widB);
        async16(b0 + 64, d + 16384 + widB);
        async16(b1 + 64, d + 24576 + widB);
    }
    #pragma unroll
    for (int h = 0; h < 2; ++h)
        #pragma unroll
        for (int j = 0; j < 4; ++j)
            cvtWrite(ABUF(0) + h * 16384 + wA[j], rA[h * 4 + j]);   // waits A(0): vmcnt(4)
    #pragma unroll
    for (int h = 0; h < 2; ++h)
        #pragma unroll
        for (int j = 0; j < 4; ++j)
            rA[h * 4 + j] = *(const f32x4*)(aBase + j * aRowStep + 64 + h * 32);
    asm volatile("s_waitcnt vmcnt(8)" ::: "memory");   // retires B(0); A(1) in flight
    asm volatile("s_waitcnt lgkmcnt(0)" ::: "memory");
    __builtin_amdgcn_s_barrier();

    for (int kt = 0; kt < nt - 2; ++kt)
        ktile<8, true,  true,  true,  true >(kt, lds, aBase, aRowStep, b0, b1, widB, aoff, boff, wA, rA, acc);
    ktile<0,  false, true,  true,  true >(nt - 2, lds, aBase, aRowStep, b0, b1, widB, aoff, boff, wA, rA, acc);
    ktile<-1, false, false, false, false>(nt - 1, lds, aBase, aRowStep, b0, b1, widB, aoff, boff, wA, rA, acc);

    // ---- fused Ghost BatchNorm + priors epilogue (wave-local; z written f16) ----
    #pragma unroll
    for (int n = 0; n < 4; ++n) {
        float s1 = 0.f, s2 = 0.f;
        #pragma unroll
        for (int m = 0; m < 8; ++m)
            #pragma unroll
            for (int j = 0; j < 4; ++j) {
                float v = acc[m][n][j];
                s1 += v; s2 += v * v;
            }
        s1 += __shfl_xor(s1, 16); s2 += __shfl_xor(s2, 16);
        s1 += __shfl_xor(s1, 32); s2 += __shfl_xor(s2, 32);
        float mean = s1 * (1.f / 128.f);
        float var  = s2 * (1.f / 128.f) - mean * mean;
        float rstd = rsqrtf(var + BN_EPS);
        const int c = col0 + wc * 64 + n * 16 + fr;
        float g = gamma[c] * rstd;
        float b = beta[c] - mean * g;
        #pragma unroll
        for (int m = 0; m < 8; ++m)
            #pragma unroll
            for (int j = 0; j < 4; ++j) {
                int r = row0 + wr * 128 + m * 16 + kg * 4 + j;
                size_t off = (size_t)r * N + c;
                Zh[off] = (_Float16)((acc[m][n][j] * g + b) * priors[off]);
            }
    }
}

// ---------------- sparsemax: one wave per row (1024), f16 input, exact Michelot ----------------
__device__ __forceinline__ float waveSum(float v) {
    #pragma unroll
    for (int off = 32; off > 0; off >>= 1) v += __shfl_xor(v, off);
    return v;
}

__global__ __launch_bounds__(256)
void sparsemax_kernel(const _Float16* __restrict__ Zh, float* __restrict__ Out) {
    const int lane = threadIdx.x & 63;
    const int wid  = threadIdx.x >> 6;
    const size_t row = (size_t)blockIdx.x * 4 + wid;
    const f16x8* zr = (const f16x8*)(Zh + row * 1024);

    float p[16];
    #pragma unroll
    for (int j = 0; j < 2; ++j) {
        f16x8 v = zr[lane * 2 + j];
        #pragma unroll
        for (int e = 0; e < 8; ++e) p[8 * j + e] = (float)v[e];
    }

    float s = 0.f;
    #pragma unroll
    for (int i = 0; i < 16; ++i) s += p[i];
    s = waveSum(s);

    float kc  = 1024.f;
    float tau = (s - 1.f) * (1.f / 1024.f);
    for (int it = 0; it < 64; ++it) {
        float s2 = 0.f, c2 = 0.f;
        #pragma unroll
        for (int i = 0; i < 16; ++i) {
            if (p[i] > tau) { s2 += p[i]; c2 += 1.f; }
        }
        s2 = waveSum(s2); c2 = waveSum(c2);
        if (c2 == kc) break;        // support stable -> tau exact
        kc = c2;
        tau = (s2 - 1.f) / c2;
    }

    float* outr = Out + row * 1024 + lane * 16;
    #pragma unroll
    for (int j = 0; j < 4; ++j) {
        float4 o;
        o.x = fmaxf(p[4 * j + 0] - tau, 0.f);
        o.y = fmaxf(p[4 * j + 1] - tau, 0.f);
        o.z = fmaxf(p[4 * j + 2] - tau, 0.f);
        o.w = fmaxf(p[4 * j + 3] - tau, 0.f);
        *(float4*)(outr + 4 * j) = o;
    }
}

extern "C" void kernel_launch(void* const* d_in, const int* in_sizes, int n_in,
                              void* d_out, int out_size, void* d_ws, size_t ws_size,
                              hipStream_t stream)
{
    const float* priors = (const float*)d_in[0];
    const float* feat   = (const float*)d_in[1];
    const float* W      = (const float*)d_in[2];
    const float* gamma  = (const float*)d_in[3];
    const float* beta   = (const float*)d_in[4];
    float* out = (float*)d_out;

    const int Nf = in_sizes[3];              // 1024
    const int Kf = in_sizes[2] / Nf;         // 2048
    const int Mr = in_sizes[1] / Kf;         // 32768

    _Float16* Wh = (_Float16*)d_ws;                                   // 4 MB
    _Float16* Zh = (_Float16*)((char*)d_ws + (size_t)Nf * Kf * 2);    // 64 MB

    {
        int n8 = Nf * (Kf / 8);
        cast_f32_f16<<<(n8 + 255) / 256, 256, 0, stream>>>(W, Wh, n8);
    }

    int nblk = (Mr / 256) * (Nf / 256);      // 512, divisible by 8
    gemm_gbn_kernel<<<nblk, 512, 0, stream>>>(feat, Wh, priors, gamma, beta, Zh, Mr, Nf, Kf);

    sparsemax_kernel<<<Mr / 4, 256, 0, stream>>>(Zh, out);
}

// Round 27
// 270.830 us; speedup vs baseline: 1.0402x; 1.0047x over previous
//
#include <hip/hip_runtime.h>
#include <hip/hip_bf16.h>
#include <cstdint>

typedef __attribute__((ext_vector_type(4))) float f32x4;
typedef _Float16 f16x8 __attribute__((ext_vector_type(8)));
typedef _Float16 f16x4 __attribute__((ext_vector_type(4)));

#define BN_EPS 1e-5f

// ---------------- fp32 -> fp16 cast (only W, 4 MB) ----------------
__global__ __launch_bounds__(256)
void cast_f32_f16(const float* __restrict__ src, _Float16* __restrict__ dst, int n8) {
    int i = blockIdx.x * blockDim.x + threadIdx.x;
    if (i >= n8) return;
    const float4* s4 = (const float4*)src;
    float4 a = s4[2 * (size_t)i];
    float4 b = s4[2 * (size_t)i + 1];
    f16x8 h;
    h[0] = (_Float16)a.x; h[1] = (_Float16)a.y; h[2] = (_Float16)a.z; h[3] = (_Float16)a.w;
    h[4] = (_Float16)b.x; h[5] = (_Float16)b.y; h[6] = (_Float16)b.z; h[7] = (_Float16)b.w;
    *(f16x8*)(dst + 8 * (size_t)i) = h;
}

// async global->LDS, 16B per lane, wave-uniform LDS base (B path)
__device__ __forceinline__ void async16(const char* g, char* l) {
    __builtin_amdgcn_global_load_lds(
        (const __attribute__((address_space(1))) unsigned int*)(uintptr_t)g,
        (__attribute__((address_space(3))) unsigned int*)(uintptr_t)l,
        16, 0, 0);
}

// ====== FINAL (r21/r24, measured best 271-272us): 256x256, BK=64, fused A-cast ======
// Session conclusions baked in:
//  - 16x16x32 MFMA with this exact read swizzle = the only measured-0-conflict pattern
//    (r25: 32x32 identical perf but 1.26e7 conflicts -> conflicts off critical path).
//  - Order (c)(a)(b)(d,e): ds_writes must precede ds_reads (r23: lgkmcnt is one FIFO;
//    interleaved writes force full drains, +10%).
//  - No setprio (r21: m190-confirmed, lockstep GEMM hurts).
//  - BK=64 > BK=32 (r20, +2%: amortizes per-tile waits/barrier).
//  - min-waves/EU = 2 (r17: acc=128 regs spills catastrophically at 4/EU).
//  - 1 block/CU optimal (r19: 2 blocks/CU = slower; per-wave work halving dominates).
// FIFO ledger per wave/tile {A=8 reg loads, B=4 asyncs}:
//   entering kt: queue [A(kt+1) 8]
//   (c) B(kt+1) 4 asyncs -> BBUF((kt+1)&1)   [queue A8,B4]
//   (a) cvt+write A(kt+1) [compiler vmcnt(4) retires A(kt+1), leaves B(kt+1)]
//   (b) A(kt+2) 8 loads                      [queue B4,A8 = 12]
//   (d) per k-half: 12 ds_read; (e) 32 MFMA  (x2 halves)
//   (f) vmcnt(8) retires B(kt+1)  (g) lgkm0; barrier
// WAR: A-write@kt -> ABUF((kt+1)&1)=ABUF((kt-1)&1), reads drained before barrier@kt-1.
//      B-async@kt -> BBUF((kt+1)&1), reads@kt-1 drained before barrier@kt-1. Safe.
// Tails: kt=nt-2: STAGEA off, vmcnt(0); kt=nt-1: compute only.

#define ABUF(t) (lds + ((t) & 1) * 32768)
#define BBUF(t) (lds + 65536 + ((t) & 1) * 32768)

__device__ __forceinline__ void cvtWrite(char* addr, const f32x4& v) {
    f16x4 h;
    h[0] = (_Float16)v[0]; h[1] = (_Float16)v[1];
    h[2] = (_Float16)v[2]; h[3] = (_Float16)v[3];
    *(f16x4*)addr = h;
}

template<int WAITN, bool STAGEA, bool STAGEB, bool WRITEA, bool BAR>
__device__ __forceinline__ void ktile(
    int kt, char* lds, const float* aBase, size_t aRowStep,
    const char* b0, const char* b1, int widB,
    int aoff, int boff, const int (&wA)[4], f32x4 (&rA)[8],
    f32x4 (&acc)[8][4])
{
    // (c) B(kt+1): 4 asyncs (two k-halves x two row-chunks)
    if (STAGEB) {
        const size_t cb = (size_t)(kt + 1) * 128;
        char* d = BBUF(kt + 1);
        async16(b0 + cb,      d + widB);
        async16(b1 + cb,      d + 8192 + widB);
        async16(b0 + cb + 64, d + 16384 + widB);
        async16(b1 + cb + 64, d + 24576 + widB);
    }
    // (a) cvt + ds_write A(kt+1) (both halves)
    if (WRITEA) {
        char* ad = ABUF(kt + 1);
        #pragma unroll
        for (int h = 0; h < 2; ++h)
            #pragma unroll
            for (int j = 0; j < 4; ++j)
                cvtWrite(ad + h * 16384 + wA[j], rA[h * 4 + j]);
    }
    // (b) A(kt+2) -> rA
    if (STAGEA) {
        #pragma unroll
        for (int h = 0; h < 2; ++h)
            #pragma unroll
            for (int j = 0; j < 4; ++j)
                rA[h * 4 + j] = *(const f32x4*)(aBase + j * aRowStep + (size_t)(kt + 2) * 64 + h * 32);
    }
    // (d,e) two k-halves: 12 ds_read + 32 MFMA each
    #pragma unroll
    for (int h = 0; h < 2; ++h) {
        f16x8 a[8], b[4];
        const char* ab = ABUF(kt) + h * 16384;
        const char* bb = BBUF(kt) + h * 16384;
        #pragma unroll
        for (int n = 0; n < 4; ++n) b[n] = *(const f16x8*)(bb + boff + n * 1024);
        #pragma unroll
        for (int m = 0; m < 8; ++m) a[m] = *(const f16x8*)(ab + aoff + m * 1024);
        #pragma unroll
        for (int m = 0; m < 8; ++m)
            #pragma unroll
            for (int n = 0; n < 4; ++n)
                acc[m][n] = __builtin_amdgcn_mfma_f32_16x16x32_f16(a[m], b[n], acc[m][n], 0, 0, 0);
    }
    // (f,g)
    if (WAITN == 8)      { asm volatile("s_waitcnt vmcnt(8)" ::: "memory"); }
    else if (WAITN == 0) { asm volatile("s_waitcnt vmcnt(0)" ::: "memory"); }
    if (BAR) {
        asm volatile("s_waitcnt lgkmcnt(0)" ::: "memory");
        __builtin_amdgcn_s_barrier();
    }
}

__global__ __launch_bounds__(512, 2)
void gemm_gbn_kernel(const float* __restrict__ Af,
                     const _Float16* __restrict__ Bw,
                     const float* __restrict__ priors,
                     const float* __restrict__ gamma,
                     const float* __restrict__ beta,
                     _Float16* __restrict__ Zh,
                     int M, int N, int K)
{
    __shared__ __align__(16) char lds[131072];   // A 2x32KB + B 2x32KB

    const int tid  = threadIdx.x;
    const int lane = tid & 63;
    const int wid  = tid >> 6;     // 0..7
    const int wr   = wid >> 2;     // 0..1  (128-row half == one virtual batch)
    const int wc   = wid & 3;      // 0..3  (64-col slice)
    const int fr   = lane & 15;
    const int kg   = lane >> 4;

    // XCD-aware bijective swizzle (512 blocks, %8==0)
    const int bid = blockIdx.x;
    const int swz = (bid & 7) * 64 + (bid >> 3);
    const int row0 = (swz >> 2) * 256;
    const int col0 = (swz & 3) * 256;

    // ---- A fused-cast staging: load (h,j) covers row (tid>>3)+j*64, k-half h, granule tid&7 ----
    const float* aBase = Af + (size_t)(row0 + (tid >> 3)) * (size_t)K + (tid & 7) * 4;
    const size_t aRowStep = (size_t)64 * K;
    int wA[4];
    {
        const int sub = tid & 7;
        #pragma unroll
        for (int j = 0; j < 4; ++j) {
            const int r = (tid >> 3) + j * 64;
            wA[j] = r * 64 + (((sub >> 1) ^ ((r >> 1) & 3)) * 16) + (sub & 1) * 8;
        }
    }

    // ---- B staging (proven gload_lds path) ----
    const int bperm = ((tid & 3) ^ ((tid >> 3) & 3)) * 16;
    const char* b0 = (const char*)Bw + (size_t)(col0 + (tid >> 2)) * (size_t)K * 2 + bperm;
    const char* b1 = b0 + (size_t)128 * K * 2;
    const int widB = wid * 1024;

    // ---- fragment read offsets (within 16KB half-buffer; measured-0-conflict swizzle) ----
    int aoff = (wr * 128 + fr) * 64 + kg * 16;
    aoff ^= ((aoff >> 7) & 3) << 4;
    int boff = (wc * 64 + fr) * 64 + kg * 16;
    boff ^= ((boff >> 7) & 3) << 4;

    f32x4 acc[8][4];
    #pragma unroll
    for (int m = 0; m < 8; ++m)
        #pragma unroll
        for (int n = 0; n < 4; ++n)
            acc[m][n] = (f32x4)0.0f;

    const int nt = K >> 6;   // 32 K-tiles of 64
    f32x4 rA[8];

    // ---- prologue: A(0); B(0); cvt+write A(0) [vmcnt(4)]; A(1); vmcnt(8) [retires B(0)] ----
    #pragma unroll
    for (int h = 0; h < 2; ++h)
        #pragma unroll
        for (int j = 0; j < 4; ++j)
            rA[h * 4 + j] = *(const f32x4*)(aBase + j * aRowStep + h * 32);
    {
        char* d = BBUF(0);
        async16(b0,      d + widB);
        async16(b1,      d + 8192 + widB);
        async16(b0 + 64, d + 16384 + widB);
        async16(b1 + 64, d + 24576 + widB);
    }
    #pragma unroll
    for (int h = 0; h < 2; ++h)
        #pragma unroll
        for (int j = 0; j < 4; ++j)
            cvtWrite(ABUF(0) + h * 16384 + wA[j], rA[h * 4 + j]);   // waits A(0): vmcnt(4)
    #pragma unroll
    for (int h = 0; h < 2; ++h)
        #pragma unroll
        for (int j = 0; j < 4; ++j)
            rA[h * 4 + j] = *(const f32x4*)(aBase + j * aRowStep + 64 + h * 32);
    asm volatile("s_waitcnt vmcnt(8)" ::: "memory");   // retires B(0); A(1) in flight
    asm volatile("s_waitcnt lgkmcnt(0)" ::: "memory");
    __builtin_amdgcn_s_barrier();

    for (int kt = 0; kt < nt - 2; ++kt)
        ktile<8, true,  true,  true,  true >(kt, lds, aBase, aRowStep, b0, b1, widB, aoff, boff, wA, rA, acc);
    ktile<0,  false, true,  true,  true >(nt - 2, lds, aBase, aRowStep, b0, b1, widB, aoff, boff, wA, rA, acc);
    ktile<-1, false, false, false, false>(nt - 1, lds, aBase, aRowStep, b0, b1, widB, aoff, boff, wA, rA, acc);

    // ---- fused Ghost BatchNorm + priors epilogue (wave-local; z written f16) ----
    #pragma unroll
    for (int n = 0; n < 4; ++n) {
        float s1 = 0.f, s2 = 0.f;
        #pragma unroll
        for (int m = 0; m < 8; ++m)
            #pragma unroll
            for (int j = 0; j < 4; ++j) {
                float v = acc[m][n][j];
                s1 += v; s2 += v * v;
            }
        s1 += __shfl_xor(s1, 16); s2 += __shfl_xor(s2, 16);
        s1 += __shfl_xor(s1, 32); s2 += __shfl_xor(s2, 32);
        float mean = s1 * (1.f / 128.f);
        float var  = s2 * (1.f / 128.f) - mean * mean;
        float rstd = rsqrtf(var + BN_EPS);
        const int c = col0 + wc * 64 + n * 16 + fr;
        float g = gamma[c] * rstd;
        float b = beta[c] - mean * g;
        #pragma unroll
        for (int m = 0; m < 8; ++m)
            #pragma unroll
            for (int j = 0; j < 4; ++j) {
                int r = row0 + wr * 128 + m * 16 + kg * 4 + j;
                size_t off = (size_t)r * N + c;
                Zh[off] = (_Float16)((acc[m][n][j] * g + b) * priors[off]);
            }
    }
}

// ---------------- sparsemax: one wave per row (1024), f16 input, exact Michelot ----------------
__device__ __forceinline__ float waveSum(float v) {
    #pragma unroll
    for (int off = 32; off > 0; off >>= 1) v += __shfl_xor(v, off);
    return v;
}

__global__ __launch_bounds__(256)
void sparsemax_kernel(const _Float16* __restrict__ Zh, float* __restrict__ Out) {
    const int lane = threadIdx.x & 63;
    const int wid  = threadIdx.x >> 6;
    const size_t row = (size_t)blockIdx.x * 4 + wid;
    const f16x8* zr = (const f16x8*)(Zh + row * 1024);

    float p[16];
    #pragma unroll
    for (int j = 0; j < 2; ++j) {
        f16x8 v = zr[lane * 2 + j];
        #pragma unroll
        for (int e = 0; e < 8; ++e) p[8 * j + e] = (float)v[e];
    }

    float s = 0.f;
    #pragma unroll
    for (int i = 0; i < 16; ++i) s += p[i];
    s = waveSum(s);

    float kc  = 1024.f;
    float tau = (s - 1.f) * (1.f / 1024.f);
    for (int it = 0; it < 64; ++it) {
        float s2 = 0.f, c2 = 0.f;
        #pragma unroll
        for (int i = 0; i < 16; ++i) {
            if (p[i] > tau) { s2 += p[i]; c2 += 1.f; }
        }
        s2 = waveSum(s2); c2 = waveSum(c2);
        if (c2 == kc) break;        // support stable -> tau exact
        kc = c2;
        tau = (s2 - 1.f) / c2;
    }

    float* outr = Out + row * 1024 + lane * 16;
    #pragma unroll
    for (int j = 0; j < 4; ++j) {
        float4 o;
        o.x = fmaxf(p[4 * j + 0] - tau, 0.f);
        o.y = fmaxf(p[4 * j + 1] - tau, 0.f);
        o.z = fmaxf(p[4 * j + 2] - tau, 0.f);
        o.w = fmaxf(p[4 * j + 3] - tau, 0.f);
        *(float4*)(outr + 4 * j) = o;
    }
}

extern "C" void kernel_launch(void* const* d_in, const int* in_sizes, int n_in,
                              void* d_out, int out_size, void* d_ws, size_t ws_size,
                              hipStream_t stream)
{
    const float* priors = (const float*)d_in[0];
    const float* feat   = (const float*)d_in[1];
    const float* W      = (const float*)d_in[2];
    const float* gamma  = (const float*)d_in[3];
    const float* beta   = (const float*)d_in[4];
    float* out = (float*)d_out;

    const int Nf = in_sizes[3];              // 1024
    const int Kf = in_sizes[2] / Nf;         // 2048
    const int Mr = in_sizes[1] / Kf;         // 32768

    _Float16* Wh = (_Float16*)d_ws;                                   // 4 MB
    _Float16* Zh = (_Float16*)((char*)d_ws + (size_t)Nf * Kf * 2);    // 64 MB

    {
        int n8 = Nf * (Kf / 8);
        cast_f32_f16<<<(n8 + 255) / 256, 256, 0, stream>>>(W, Wh, n8);
    }

    int nblk = (Mr / 256) * (Nf / 256);      // 512, divisible by 8
    gemm_gbn_kernel<<<nblk, 512, 0, stream>>>(feat, Wh, priors, gamma, beta, Zh, Mr, Nf, Kf);

    sparsemax_kernel<<<Mr / 4, 256, 0, stream>>>(Zh, out);
}